// Round 1
// baseline (1508.458 us; speedup 1.0000x reference)
//
#include <hip/hip_runtime.h>
#include <math.h>

#define N_NODES 100000
#define N_EDGES 1250000
#define IN_DIM 12
#define HID 64
#define N_LAYERS 3
#define LN_EPS 1e-5f
#define SLOPE 0.01f

#define NODE_BLOCKS ((N_NODES + 3) / 4)     // 4 waves (nodes) per 256-thread block
#define EDGE_TBLOCKS ((N_EDGES + 255) / 256)
#define EDGE_WBLOCKS ((N_EDGES + 3) / 4)

// ---------------- input projection: h = x @ in_W + in_b ----------------
// one wave (64 lanes) per node; lane j computes h[n][j]
__global__ void k_in_proj(const float* __restrict__ x,
                          const float* __restrict__ W,   // [12][64]
                          const float* __restrict__ b,
                          float* __restrict__ h) {
  __shared__ float sW[IN_DIM * HID];
  for (int i = threadIdx.x; i < IN_DIM * HID; i += blockDim.x) sW[i] = W[i];
  __syncthreads();
  int wave = threadIdx.x >> 6, lane = threadIdx.x & 63;
  int n = blockIdx.x * 4 + wave;
  if (n >= N_NODES) return;
  float acc = b[lane];
#pragma unroll
  for (int k = 0; k < IN_DIM; ++k)
    acc += x[n * IN_DIM + k] * sW[k * HID + lane];
  h[n * HID + lane] = acc;
}

// ---------------- per-layer linear + attention alphas ----------------
// hl = h @ W + bias ; alpha1[n] = dot(hl[n], attW[:64]) ; alpha2[n] = dot(hl[n], attW[64:])
__global__ void k_lin(const float* __restrict__ h,
                      const float* __restrict__ W,     // [64][64]
                      const float* __restrict__ bias,  // [64]
                      const float* __restrict__ attW,  // [128]
                      float* __restrict__ hl,
                      float* __restrict__ alpha1,
                      float* __restrict__ alpha2) {
  __shared__ float sW[HID * HID];
  for (int i = threadIdx.x; i < HID * HID; i += blockDim.x) sW[i] = W[i];
  __syncthreads();
  int wave = threadIdx.x >> 6, lane = threadIdx.x & 63;
  int n = blockIdx.x * 4 + wave;
  if (n >= N_NODES) return;
  float hreg = h[n * HID + lane];
  float acc = bias[lane];
#pragma unroll
  for (int k = 0; k < HID; ++k) {
    float hk = __shfl(hreg, k, 64);
    acc += hk * sW[k * HID + lane];
  }
  hl[n * HID + lane] = acc;
  float p1 = acc * attW[lane];
  float p2 = acc * attW[HID + lane];
#pragma unroll
  for (int off = 32; off > 0; off >>= 1) {
    p1 += __shfl_xor(p1, off, 64);
    p2 += __shfl_xor(p2, off, 64);
  }
  if (lane == 0) { alpha1[n] = p1; alpha2[n] = p2; }
}

// ---------------- edge scores + block max partials ----------------
__global__ void k_score(const int* __restrict__ ei,     // [2][E]
                        const float* __restrict__ alpha1,
                        const float* __restrict__ alpha2,
                        const float* __restrict__ attB,  // scalar
                        float* __restrict__ s,
                        float* __restrict__ partial) {
  __shared__ float red[256];
  int e = blockIdx.x * 256 + threadIdx.x;
  float v = -INFINITY;
  if (e < N_EDGES) {
    int r = ei[e], c = ei[N_EDGES + e];
    float sc = alpha1[r] + alpha2[c] + attB[0];
    sc = sc > 0.f ? sc : SLOPE * sc;
    s[e] = sc;
    v = sc;
  }
  red[threadIdx.x] = v;
  __syncthreads();
  for (int st = 128; st > 0; st >>= 1) {
    if (threadIdx.x < st) red[threadIdx.x] = fmaxf(red[threadIdx.x], red[threadIdx.x + st]);
    __syncthreads();
  }
  if (threadIdx.x == 0) partial[blockIdx.x] = red[0];
}

__global__ void k_reduce_max(const float* __restrict__ partial, int n, float* __restrict__ red) {
  __shared__ float sm[1024];
  float v = -INFINITY;
  for (int i = threadIdx.x; i < n; i += 1024) v = fmaxf(v, partial[i]);
  sm[threadIdx.x] = v;
  __syncthreads();
  for (int st = 512; st > 0; st >>= 1) {
    if (threadIdx.x < st) sm[threadIdx.x] = fmaxf(sm[threadIdx.x], sm[threadIdx.x + st]);
    __syncthreads();
  }
  if (threadIdx.x == 0) red[0] = sm[0];
}

// ---------------- exp(s - max), overwrite s, block sum partials ----------------
__global__ void k_exp(float* __restrict__ s,
                      const float* __restrict__ red,   // red[0] = max
                      float* __restrict__ partial) {
  __shared__ float sm[256];
  int e = blockIdx.x * 256 + threadIdx.x;
  float v = 0.f;
  if (e < N_EDGES) {
    float p = expf(s[e] - red[0]);
    s[e] = p;
    v = p;
  }
  sm[threadIdx.x] = v;
  __syncthreads();
  for (int st = 128; st > 0; st >>= 1) {
    if (threadIdx.x < st) sm[threadIdx.x] += sm[threadIdx.x + st];
    __syncthreads();
  }
  if (threadIdx.x == 0) partial[blockIdx.x] = sm[0];
}

__global__ void k_reduce_sum(const float* __restrict__ partial, int n, float* __restrict__ red) {
  __shared__ float sm[1024];
  float v = 0.f;
  for (int i = threadIdx.x; i < n; i += 1024) v += partial[i];
  sm[threadIdx.x] = v;
  __syncthreads();
  for (int st = 512; st > 0; st >>= 1) {
    if (threadIdx.x < st) sm[threadIdx.x] += sm[threadIdx.x + st];
    __syncthreads();
  }
  if (threadIdx.x == 0) red[0] = sm[0];
}

// ---------------- scatter: agg[row] += (p*ew/sum) * hl[col] ----------------
// one wave per edge; lane j handles channel j
__global__ void k_scatter(const int* __restrict__ ei,
                          const float* __restrict__ s,   // p = exp(s-max)
                          const float* __restrict__ ew,
                          const float* __restrict__ red, // red[1] = sumexp
                          const float* __restrict__ hl,
                          float* __restrict__ agg) {
  int wave = threadIdx.x >> 6, lane = threadIdx.x & 63;
  int e = blockIdx.x * 4 + wave;
  if (e >= N_EDGES) return;
  float w = s[e] * ew[e] / red[1];
  int r = ei[e], c = ei[N_EDGES + e];
  atomicAdd(&agg[r * HID + lane], w * hl[c * HID + lane]);
}

// ---------------- node update: h += LN(relu(hl + agg)) ----------------
__global__ void k_update(const float* __restrict__ hl,
                         const float* __restrict__ agg,
                         const float* __restrict__ g,
                         const float* __restrict__ b,
                         float* __restrict__ h) {
  int wave = threadIdx.x >> 6, lane = threadIdx.x & 63;
  int n = blockIdx.x * 4 + wave;
  if (n >= N_NODES) return;
  float v = hl[n * HID + lane] + agg[n * HID + lane];
  v = fmaxf(v, 0.f);
  float m = v;
#pragma unroll
  for (int off = 32; off > 0; off >>= 1) m += __shfl_xor(m, off, 64);
  m *= (1.0f / HID);
  float d = v - m;
  float var = d * d;
#pragma unroll
  for (int off = 32; off > 0; off >>= 1) var += __shfl_xor(var, off, 64);
  var *= (1.0f / HID);
  float nv = d * rsqrtf(var + LN_EPS);
  h[n * HID + lane] += nv * g[lane] + b[lane];
}

// ---------------- output head ----------------
// wave per node; lane m (and m+32 duplicate) computes z_m; reduce relu(z)*W2
__global__ void k_out(const float* __restrict__ h,
                      const float* __restrict__ W1,  // [64][32]
                      const float* __restrict__ b1,  // [32]
                      const float* __restrict__ W2,  // [32]
                      const float* __restrict__ b2,  // [1]
                      float* __restrict__ out) {
  __shared__ float sW1[HID * 32];
  __shared__ float sW2[32];
  for (int i = threadIdx.x; i < HID * 32; i += blockDim.x) sW1[i] = W1[i];
  if (threadIdx.x < 32) sW2[threadIdx.x] = W2[threadIdx.x];
  __syncthreads();
  int wave = threadIdx.x >> 6, lane = threadIdx.x & 63;
  int n = blockIdx.x * 4 + wave;
  if (n >= N_NODES) return;
  float hreg = h[n * HID + lane];
  int m = lane & 31;
  float z = b1[m];
#pragma unroll
  for (int k = 0; k < HID; ++k)
    z += __shfl(hreg, k, 64) * sW1[k * 32 + m];
  float part = fmaxf(z, 0.f) * sW2[m] * 0.5f;  // each m counted twice across 64 lanes
#pragma unroll
  for (int off = 32; off > 0; off >>= 1) part += __shfl_xor(part, off, 64);
  if (lane == 0) {
    float t = part + b2[0];
    out[n] = 1.0f / (1.0f + expf(-t));
  }
}

extern "C" void kernel_launch(void* const* d_in, const int* in_sizes, int n_in,
                              void* d_out, int out_size, void* d_ws, size_t ws_size,
                              hipStream_t stream) {
  const float* x      = (const float*)d_in[0];
  const int*   ei     = (const int*)d_in[1];     // [2][E]
  const float* ew     = (const float*)d_in[2];
  const float* in_W   = (const float*)d_in[3];
  const float* in_b   = (const float*)d_in[4];
  const float* lin_W  = (const float*)d_in[5];   // [3][64][64]
  const float* lin_b  = (const float*)d_in[6];   // [3][64]
  const float* att_W  = (const float*)d_in[7];   // [3][128]
  const float* att_b  = (const float*)d_in[8];   // [3]
  const float* ln_g   = (const float*)d_in[9];   // [3][64]
  const float* ln_b   = (const float*)d_in[10];  // [3][64]
  const float* out1_W = (const float*)d_in[11];  // [64][32]
  const float* out1_b = (const float*)d_in[12];  // [32]
  const float* out2_W = (const float*)d_in[13];  // [32]
  const float* out2_b = (const float*)d_in[14];  // [1]
  float* out = (float*)d_out;

  float* ws = (float*)d_ws;
  float* h      = ws;                   // 6.4M
  float* hl     = h + (size_t)N_NODES * HID;
  float* agg    = hl + (size_t)N_NODES * HID;
  float* alpha1 = agg + (size_t)N_NODES * HID;
  float* alpha2 = alpha1 + N_NODES;
  float* s      = alpha2 + N_NODES;     // 1.25M
  float* part   = s + N_EDGES;          // 8192
  float* red    = part + 8192;          // [0]=max, [1]=sum

  k_in_proj<<<NODE_BLOCKS, 256, 0, stream>>>(x, in_W, in_b, h);

  for (int i = 0; i < N_LAYERS; ++i) {
    k_lin<<<NODE_BLOCKS, 256, 0, stream>>>(h, lin_W + i * HID * HID, lin_b + i * HID,
                                           att_W + i * 2 * HID, hl, alpha1, alpha2);
    k_score<<<EDGE_TBLOCKS, 256, 0, stream>>>(ei, alpha1, alpha2, att_b + i, s, part);
    k_reduce_max<<<1, 1024, 0, stream>>>(part, EDGE_TBLOCKS, red);
    k_exp<<<EDGE_TBLOCKS, 256, 0, stream>>>(s, red, part);
    k_reduce_sum<<<1, 1024, 0, stream>>>(part, EDGE_TBLOCKS, red + 1);
    hipMemsetAsync(agg, 0, (size_t)N_NODES * HID * sizeof(float), stream);
    k_scatter<<<EDGE_WBLOCKS, 256, 0, stream>>>(ei, s, ew, red, hl, agg);
    k_update<<<NODE_BLOCKS, 256, 0, stream>>>(hl, agg, ln_g + i * HID, ln_b + i * HID, h);
  }

  k_out<<<NODE_BLOCKS, 256, 0, stream>>>(h, out1_W, out1_b, out2_W, out2_b, out);
}

// Round 2
// 1020.529 us; speedup vs baseline: 1.4781x; 1.4781x over previous
//
#include <hip/hip_runtime.h>
#include <math.h>

#define N_NODES 100000
#define N_EDGES 1250000
#define IN_DIM 12
#define HID 64
#define N_LAYERS 3
#define LN_EPS 1e-5f
#define SLOPE 0.01f

#define NODE_BLOCKS ((N_NODES + 3) / 4)     // 4 waves (nodes) per 256-thread block
#define EDGE_TBLOCKS ((N_EDGES + 255) / 256)
#define SCAN_BLOCKS ((N_NODES + 1023) / 1024)   // 98

// ---------------- input projection: h = x @ in_W + in_b ----------------
__global__ void k_in_proj(const float* __restrict__ x,
                          const float* __restrict__ W,   // [12][64]
                          const float* __restrict__ b,
                          float* __restrict__ h) {
  __shared__ float sW[IN_DIM * HID];
  for (int i = threadIdx.x; i < IN_DIM * HID; i += blockDim.x) sW[i] = W[i];
  __syncthreads();
  int wave = threadIdx.x >> 6, lane = threadIdx.x & 63;
  int n = blockIdx.x * 4 + wave;
  if (n >= N_NODES) return;
  float acc = b[lane];
#pragma unroll
  for (int k = 0; k < IN_DIM; ++k)
    acc += x[n * IN_DIM + k] * sW[k * HID + lane];
  h[n * HID + lane] = acc;
}

// ---------------- CSR build (once per launch) ----------------
__global__ void k_hist(const int* __restrict__ ei, int* __restrict__ deg) {
  int e = blockIdx.x * 256 + threadIdx.x;
  if (e >= N_EDGES) return;
  atomicAdd(&deg[ei[e]], 1);
}

__global__ void k_blocksums(const int* __restrict__ deg, int* __restrict__ bsum) {
  __shared__ int sm[1024];
  int i = blockIdx.x * 1024 + threadIdx.x;
  sm[threadIdx.x] = (i < N_NODES) ? deg[i] : 0;
  __syncthreads();
  for (int st = 512; st > 0; st >>= 1) {
    if (threadIdx.x < st) sm[threadIdx.x] += sm[threadIdx.x + st];
    __syncthreads();
  }
  if (threadIdx.x == 0) bsum[blockIdx.x] = sm[0];
}

__global__ void k_scan_bsums(int* __restrict__ bsum, int nb) {  // single block, 128 thr
  __shared__ int sm[128];
  int v = (threadIdx.x < nb) ? bsum[threadIdx.x] : 0;
  sm[threadIdx.x] = v;
  __syncthreads();
  for (int st = 1; st < 128; st <<= 1) {
    int t = (threadIdx.x >= st) ? sm[threadIdx.x - st] : 0;
    __syncthreads();
    sm[threadIdx.x] += t;
    __syncthreads();
  }
  if (threadIdx.x < nb) bsum[threadIdx.x] = sm[threadIdx.x] - v;  // exclusive
}

__global__ void k_scan_final(const int* __restrict__ deg, const int* __restrict__ bsum,
                             int* __restrict__ rowptr, int* __restrict__ cursor) {
  __shared__ int sm[1024];
  int i = blockIdx.x * 1024 + threadIdx.x;
  int v = (i < N_NODES) ? deg[i] : 0;
  sm[threadIdx.x] = v;
  __syncthreads();
  for (int st = 1; st < 1024; st <<= 1) {
    int t = (threadIdx.x >= st) ? sm[threadIdx.x - st] : 0;
    __syncthreads();
    sm[threadIdx.x] += t;
    __syncthreads();
  }
  int excl = sm[threadIdx.x] - v + bsum[blockIdx.x];
  if (i < N_NODES) { rowptr[i] = excl; cursor[i] = excl; }
}

__global__ void k_fill(const int* __restrict__ ei, int* __restrict__ cursor,
                       int* __restrict__ col_sorted, int* __restrict__ pos) {
  int e = blockIdx.x * 256 + threadIdx.x;
  if (e >= N_EDGES) return;
  int r = ei[e], c = ei[N_EDGES + e];
  int p = atomicAdd(&cursor[r], 1);
  col_sorted[p] = c;
  pos[e] = p;
}

// ---------------- per-layer linear + attention alphas ----------------
__global__ void k_lin(const float* __restrict__ h,
                      const float* __restrict__ W,     // [64][64]
                      const float* __restrict__ bias,  // [64]
                      const float* __restrict__ attW,  // [128]
                      float* __restrict__ hl,
                      float* __restrict__ alpha1,
                      float* __restrict__ alpha2) {
  __shared__ float sW[HID * HID];
  for (int i = threadIdx.x; i < HID * HID; i += blockDim.x) sW[i] = W[i];
  __syncthreads();
  int wave = threadIdx.x >> 6, lane = threadIdx.x & 63;
  int n = blockIdx.x * 4 + wave;
  if (n >= N_NODES) return;
  float hreg = h[n * HID + lane];
  float acc = bias[lane];
#pragma unroll
  for (int k = 0; k < HID; ++k) {
    float hk = __shfl(hreg, k, 64);
    acc += hk * sW[k * HID + lane];
  }
  hl[n * HID + lane] = acc;
  float p1 = acc * attW[lane];
  float p2 = acc * attW[HID + lane];
#pragma unroll
  for (int off = 32; off > 0; off >>= 1) {
    p1 += __shfl_xor(p1, off, 64);
    p2 += __shfl_xor(p2, off, 64);
  }
  if (lane == 0) { alpha1[n] = p1; alpha2[n] = p2; }
}

// ---------------- edge scores + block max partials ----------------
__global__ void k_score(const int* __restrict__ ei,
                        const float* __restrict__ alpha1,
                        const float* __restrict__ alpha2,
                        const float* __restrict__ attB,
                        float* __restrict__ s,
                        float* __restrict__ partial) {
  __shared__ float red[256];
  int e = blockIdx.x * 256 + threadIdx.x;
  float v = -INFINITY;
  if (e < N_EDGES) {
    int r = ei[e], c = ei[N_EDGES + e];
    float sc = alpha1[r] + alpha2[c] + attB[0];
    sc = sc > 0.f ? sc : SLOPE * sc;
    s[e] = sc;
    v = sc;
  }
  red[threadIdx.x] = v;
  __syncthreads();
  for (int st = 128; st > 0; st >>= 1) {
    if (threadIdx.x < st) red[threadIdx.x] = fmaxf(red[threadIdx.x], red[threadIdx.x + st]);
    __syncthreads();
  }
  if (threadIdx.x == 0) partial[blockIdx.x] = red[0];
}

__global__ void k_reduce_max(const float* __restrict__ partial, int n, float* __restrict__ red) {
  __shared__ float sm[1024];
  float v = -INFINITY;
  for (int i = threadIdx.x; i < n; i += 1024) v = fmaxf(v, partial[i]);
  sm[threadIdx.x] = v;
  __syncthreads();
  for (int st = 512; st > 0; st >>= 1) {
    if (threadIdx.x < st) sm[threadIdx.x] = fmaxf(sm[threadIdx.x], sm[threadIdx.x + st]);
    __syncthreads();
  }
  if (threadIdx.x == 0) red[0] = sm[0];
}

// ---------------- p = exp(s-max); coef[pos[e]] = p*ew; block-sum p ----------------
__global__ void k_exp(const float* __restrict__ s,
                      const float* __restrict__ red,   // red[0] = max
                      const float* __restrict__ ew,
                      const int* __restrict__ pos,
                      float* __restrict__ coef,
                      float* __restrict__ partial) {
  __shared__ float sm[256];
  int e = blockIdx.x * 256 + threadIdx.x;
  float v = 0.f;
  if (e < N_EDGES) {
    float p = expf(s[e] - red[0]);
    coef[pos[e]] = p * ew[e];
    v = p;
  }
  sm[threadIdx.x] = v;
  __syncthreads();
  for (int st = 128; st > 0; st >>= 1) {
    if (threadIdx.x < st) sm[threadIdx.x] += sm[threadIdx.x + st];
    __syncthreads();
  }
  if (threadIdx.x == 0) partial[blockIdx.x] = sm[0];
}

__global__ void k_reduce_sum(const float* __restrict__ partial, int n, float* __restrict__ red) {
  __shared__ float sm[1024];
  float v = 0.f;
  for (int i = threadIdx.x; i < n; i += 1024) v += partial[i];
  sm[threadIdx.x] = v;
  __syncthreads();
  for (int st = 512; st > 0; st >>= 1) {
    if (threadIdx.x < st) sm[threadIdx.x] += sm[threadIdx.x + st];
    __syncthreads();
  }
  if (threadIdx.x == 0) red[0] = sm[0];
}

// ---------------- fused CSR aggregate + relu + LN + residual ----------------
// one wave per node; lane j = channel j
__global__ void k_agg_update(const int* __restrict__ rowptr,
                             const int* __restrict__ deg,
                             const int* __restrict__ col_sorted,
                             const float* __restrict__ coef,
                             const float* __restrict__ red,  // red[1] = sumexp
                             const float* __restrict__ hl,
                             const float* __restrict__ g,
                             const float* __restrict__ b,
                             float* __restrict__ h) {
  int wave = threadIdx.x >> 6, lane = threadIdx.x & 63;
  int n = blockIdx.x * 4 + wave;
  if (n >= N_NODES) return;
  int beg = rowptr[n];
  int end = beg + deg[n];
  float acc = 0.f;
  int k = beg;
  for (; k + 1 < end; k += 2) {  // 2-way unroll for load ILP
    int c0 = col_sorted[k], c1 = col_sorted[k + 1];
    float w0 = coef[k], w1 = coef[k + 1];
    float v0 = hl[(size_t)c0 * HID + lane];
    float v1 = hl[(size_t)c1 * HID + lane];
    acc += w0 * v0;
    acc += w1 * v1;
  }
  if (k < end) acc += coef[k] * hl[(size_t)col_sorted[k] * HID + lane];

  float inv = 1.0f / red[1];
  float v = hl[(size_t)n * HID + lane] + acc * inv;
  v = fmaxf(v, 0.f);
  float m = v;
#pragma unroll
  for (int off = 32; off > 0; off >>= 1) m += __shfl_xor(m, off, 64);
  m *= (1.0f / HID);
  float d = v - m;
  float var = d * d;
#pragma unroll
  for (int off = 32; off > 0; off >>= 1) var += __shfl_xor(var, off, 64);
  var *= (1.0f / HID);
  float nv = d * rsqrtf(var + LN_EPS);
  h[(size_t)n * HID + lane] += nv * g[lane] + b[lane];
}

// ---------------- output head ----------------
__global__ void k_out(const float* __restrict__ h,
                      const float* __restrict__ W1,  // [64][32]
                      const float* __restrict__ b1,  // [32]
                      const float* __restrict__ W2,  // [32]
                      const float* __restrict__ b2,  // [1]
                      float* __restrict__ out) {
  __shared__ float sW1[HID * 32];
  __shared__ float sW2[32];
  for (int i = threadIdx.x; i < HID * 32; i += blockDim.x) sW1[i] = W1[i];
  if (threadIdx.x < 32) sW2[threadIdx.x] = W2[threadIdx.x];
  __syncthreads();
  int wave = threadIdx.x >> 6, lane = threadIdx.x & 63;
  int n = blockIdx.x * 4 + wave;
  if (n >= N_NODES) return;
  float hreg = h[n * HID + lane];
  int m = lane & 31;
  float z = b1[m];
#pragma unroll
  for (int k = 0; k < HID; ++k)
    z += __shfl(hreg, k, 64) * sW1[k * 32 + m];
  float part = fmaxf(z, 0.f) * sW2[m] * 0.5f;
#pragma unroll
  for (int off = 32; off > 0; off >>= 1) part += __shfl_xor(part, off, 64);
  if (lane == 0) {
    float t = part + b2[0];
    out[n] = 1.0f / (1.0f + expf(-t));
  }
}

extern "C" void kernel_launch(void* const* d_in, const int* in_sizes, int n_in,
                              void* d_out, int out_size, void* d_ws, size_t ws_size,
                              hipStream_t stream) {
  const float* x      = (const float*)d_in[0];
  const int*   ei     = (const int*)d_in[1];     // [2][E]
  const float* ew     = (const float*)d_in[2];
  const float* in_W   = (const float*)d_in[3];
  const float* in_b   = (const float*)d_in[4];
  const float* lin_W  = (const float*)d_in[5];   // [3][64][64]
  const float* lin_b  = (const float*)d_in[6];   // [3][64]
  const float* att_W  = (const float*)d_in[7];   // [3][128]
  const float* att_b  = (const float*)d_in[8];   // [3]
  const float* ln_g   = (const float*)d_in[9];   // [3][64]
  const float* ln_b   = (const float*)d_in[10];  // [3][64]
  const float* out1_W = (const float*)d_in[11];  // [64][32]
  const float* out1_b = (const float*)d_in[12];  // [32]
  const float* out2_W = (const float*)d_in[13];  // [32]
  const float* out2_b = (const float*)d_in[14];  // [1]
  float* out = (float*)d_out;

  float* ws = (float*)d_ws;
  float* h      = ws;                          // 6.4M f
  float* hl     = h + (size_t)N_NODES * HID;   // 6.4M f
  float* coef   = hl + (size_t)N_NODES * HID;  // 1.25M f
  float* alpha1 = coef + N_EDGES;
  float* alpha2 = alpha1 + N_NODES;
  float* s      = alpha2 + N_NODES;            // 1.25M f
  float* part   = s + N_EDGES;                 // 8192
  float* red    = part + 8192;                 // [0]=max, [1]=sum
  int* deg        = (int*)(red + 2);
  int* rowptr     = deg + N_NODES;
  int* cursor     = rowptr + N_NODES;
  int* col_sorted = cursor + N_NODES;          // 1.25M i
  int* pos        = col_sorted + N_EDGES;      // 1.25M i
  int* bsum       = pos + N_EDGES;             // 128

  // ---- one-time CSR build ----
  hipMemsetAsync(deg, 0, N_NODES * sizeof(int), stream);
  k_hist<<<EDGE_TBLOCKS, 256, 0, stream>>>(ei, deg);
  k_blocksums<<<SCAN_BLOCKS, 1024, 0, stream>>>(deg, bsum);
  k_scan_bsums<<<1, 128, 0, stream>>>(bsum, SCAN_BLOCKS);
  k_scan_final<<<SCAN_BLOCKS, 1024, 0, stream>>>(deg, bsum, rowptr, cursor);
  k_fill<<<EDGE_TBLOCKS, 256, 0, stream>>>(ei, cursor, col_sorted, pos);

  k_in_proj<<<NODE_BLOCKS, 256, 0, stream>>>(x, in_W, in_b, h);

  for (int i = 0; i < N_LAYERS; ++i) {
    k_lin<<<NODE_BLOCKS, 256, 0, stream>>>(h, lin_W + i * HID * HID, lin_b + i * HID,
                                           att_W + i * 2 * HID, hl, alpha1, alpha2);
    k_score<<<EDGE_TBLOCKS, 256, 0, stream>>>(ei, alpha1, alpha2, att_b + i, s, part);
    k_reduce_max<<<1, 1024, 0, stream>>>(part, EDGE_TBLOCKS, red);
    k_exp<<<EDGE_TBLOCKS, 256, 0, stream>>>(s, red, ew, pos, coef, part);
    k_reduce_sum<<<1, 1024, 0, stream>>>(part, EDGE_TBLOCKS, red + 1);
    k_agg_update<<<NODE_BLOCKS, 256, 0, stream>>>(rowptr, deg, col_sorted, coef, red,
                                                  hl, ln_g + i * HID, ln_b + i * HID, h);
  }

  k_out<<<NODE_BLOCKS, 256, 0, stream>>>(h, out1_W, out1_b, out2_W, out2_b, out);
}

// Round 3
// 710.252 us; speedup vs baseline: 2.1238x; 1.4369x over previous
//
#include <hip/hip_runtime.h>
#include <math.h>

#define N_NODES 100000
#define N_EDGES 1250000
#define IN_DIM 12
#define HID 64
#define N_LAYERS 3
#define LN_EPS 1e-5f
#define SLOPE 0.01f

#define NODE_BLOCKS ((N_NODES + 3) / 4)     // 4 waves (nodes) per 256-thread block
#define EDGE_TBLOCKS ((N_EDGES + 255) / 256)
#define SCAN_BLOCKS ((N_NODES + 1023) / 1024)   // 98
#define MFMA_BLOCKS ((N_NODES + 63) / 64)       // 64 nodes per 256-thread block

typedef short bf16x8 __attribute__((ext_vector_type(8)));
typedef float f32x4 __attribute__((ext_vector_type(4)));

static __device__ __forceinline__ unsigned short f2bf(float f) {
  union { float f; unsigned int u; } v; v.f = f;
  unsigned int r = v.u + 0x7FFFu + ((v.u >> 16) & 1u);   // RNE
  return (unsigned short)(r >> 16);
}

// ---------------- input projection: h = x @ in_W + in_b ----------------
__global__ void k_in_proj(const float* __restrict__ x,
                          const float* __restrict__ W,   // [12][64]
                          const float* __restrict__ b,
                          float* __restrict__ h) {
  __shared__ float sW[IN_DIM * HID];
  for (int i = threadIdx.x; i < IN_DIM * HID; i += blockDim.x) sW[i] = W[i];
  __syncthreads();
  int wave = threadIdx.x >> 6, lane = threadIdx.x & 63;
  int n = blockIdx.x * 4 + wave;
  if (n >= N_NODES) return;
  float acc = b[lane];
#pragma unroll
  for (int k = 0; k < IN_DIM; ++k)
    acc += x[n * IN_DIM + k] * sW[k * HID + lane];
  h[n * HID + lane] = acc;
}

// ---------------- CSR build (once per launch) ----------------
__global__ void k_hist(const int* __restrict__ ei, int* __restrict__ deg) {
  int e = blockIdx.x * 256 + threadIdx.x;
  if (e >= N_EDGES) return;
  atomicAdd(&deg[ei[e]], 1);
}

__global__ void k_blocksums(const int* __restrict__ deg, int* __restrict__ bsum) {
  __shared__ int sm[1024];
  int i = blockIdx.x * 1024 + threadIdx.x;
  sm[threadIdx.x] = (i < N_NODES) ? deg[i] : 0;
  __syncthreads();
  for (int st = 512; st > 0; st >>= 1) {
    if (threadIdx.x < st) sm[threadIdx.x] += sm[threadIdx.x + st];
    __syncthreads();
  }
  if (threadIdx.x == 0) bsum[blockIdx.x] = sm[0];
}

__global__ void k_scan_bsums(int* __restrict__ bsum, int nb) {  // single block, 128 thr
  __shared__ int sm[128];
  int v = (threadIdx.x < nb) ? bsum[threadIdx.x] : 0;
  sm[threadIdx.x] = v;
  __syncthreads();
  for (int st = 1; st < 128; st <<= 1) {
    int t = (threadIdx.x >= st) ? sm[threadIdx.x - st] : 0;
    __syncthreads();
    sm[threadIdx.x] += t;
    __syncthreads();
  }
  if (threadIdx.x < nb) bsum[threadIdx.x] = sm[threadIdx.x] - v;  // exclusive
}

__global__ void k_scan_final(const int* __restrict__ deg, const int* __restrict__ bsum,
                             int* __restrict__ rowptr, int* __restrict__ cursor) {
  __shared__ int sm[1024];
  int i = blockIdx.x * 1024 + threadIdx.x;
  int v = (i < N_NODES) ? deg[i] : 0;
  sm[threadIdx.x] = v;
  __syncthreads();
  for (int st = 1; st < 1024; st <<= 1) {
    int t = (threadIdx.x >= st) ? sm[threadIdx.x - st] : 0;
    __syncthreads();
    sm[threadIdx.x] += t;
    __syncthreads();
  }
  int excl = sm[threadIdx.x] - v + bsum[blockIdx.x];
  if (i < N_NODES) { rowptr[i] = excl; cursor[i] = excl; }
}

__global__ void k_fill(const int* __restrict__ ei, int* __restrict__ cursor,
                       int* __restrict__ col_sorted, int* __restrict__ pos) {
  int e = blockIdx.x * 256 + threadIdx.x;
  if (e >= N_EDGES) return;
  int r = ei[e], c = ei[N_EDGES + e];
  int p = atomicAdd(&cursor[r], 1);
  col_sorted[p] = c;
  pos[e] = p;
}

// ---------------- per-layer u = W @ a  (alpha decomposition) ----------------
// alpha1[n] = hl[n]·a1 = h[n]·(W a1) + b·a1 ; one block per layer, 64 threads
__global__ void k_prep(const float* __restrict__ lin_W,  // [3][64][64]
                       const float* __restrict__ lin_b,  // [3][64]
                       const float* __restrict__ att_W,  // [3][128]
                       float* __restrict__ uvec,         // [3][2][64]
                       float* __restrict__ ucst) {       // [3][2]
  int l = blockIdx.x, j = threadIdx.x;
  const float* Wl = lin_W + l * HID * HID;
  const float* a1 = att_W + l * 2 * HID;
  const float* a2 = a1 + HID;
  float s1 = 0.f, s2 = 0.f;
  for (int c = 0; c < HID; ++c) {
    float w = Wl[j * HID + c];
    s1 += w * a1[c];
    s2 += w * a2[c];
  }
  uvec[l * 128 + j] = s1;
  uvec[l * 128 + 64 + j] = s2;
  float t1 = lin_b[l * HID + j] * a1[j];
  float t2 = lin_b[l * HID + j] * a2[j];
#pragma unroll
  for (int off = 32; off > 0; off >>= 1) {
    t1 += __shfl_xor(t1, off, 64);
    t2 += __shfl_xor(t2, off, 64);
  }
  if (j == 0) { ucst[l * 2] = t1; ucst[l * 2 + 1] = t2; }
}

// ---------------- MFMA linear: hl = h@W + b ; alphas from fp32 h ----------------
// block = 256 thr (4 waves), 64 nodes; wave tile = 16 nodes x 64 channels
__global__ void k_lin_mfma(const float* __restrict__ h,
                           const float* __restrict__ W,     // [64][64] this layer
                           const float* __restrict__ bias,  // [64]
                           const float* __restrict__ uvec,  // [2][64] this layer
                           const float* __restrict__ ucst,  // [2]
                           float* __restrict__ hl,
                           float* __restrict__ alpha1,
                           float* __restrict__ alpha2) {
  __shared__ unsigned short Wt[HID * 72];  // Wt[n][k] bf16, row stride 72 (2-way conflict = free)
  for (int idx = threadIdx.x; idx < HID * HID; idx += 256) {
    int k = idx >> 6, n = idx & 63;
    Wt[n * 72 + k] = f2bf(W[idx]);
  }
  __syncthreads();

  int wave = threadIdx.x >> 6, lane = threadIdx.x & 63;
  int g = lane >> 4, r = lane & 15;
  int nb = blockIdx.x * 64 + wave * 16;
  int row = nb + r;
  bool rowok = row < N_NODES;

  f32x4 f0 = {0,0,0,0}, f1 = {0,0,0,0}, f2v = {0,0,0,0}, f3 = {0,0,0,0};
  if (rowok) {
    const float* hrow = h + (size_t)row * HID;
    f0  = *(const f32x4*)(hrow + g * 8);
    f1  = *(const f32x4*)(hrow + g * 8 + 4);
    f2v = *(const f32x4*)(hrow + 32 + g * 8);
    f3  = *(const f32x4*)(hrow + 32 + g * 8 + 4);
  }
  bf16x8 a0, a1f;
#pragma unroll
  for (int i = 0; i < 4; ++i) {
    a0[i]      = (short)f2bf(f0[i]);
    a0[i + 4]  = (short)f2bf(f1[i]);
    a1f[i]     = (short)f2bf(f2v[i]);
    a1f[i + 4] = (short)f2bf(f3[i]);
  }

  f32x4 acc[4] = {{0,0,0,0},{0,0,0,0},{0,0,0,0},{0,0,0,0}};
#pragma unroll
  for (int nt = 0; nt < 4; ++nt) {
    bf16x8 b0 = *(const bf16x8*)&Wt[(nt * 16 + r) * 72 + g * 8];
    bf16x8 b1 = *(const bf16x8*)&Wt[(nt * 16 + r) * 72 + 32 + g * 8];
    acc[nt] = __builtin_amdgcn_mfma_f32_16x16x32_bf16(a0, b0, acc[nt], 0, 0, 0);
    acc[nt] = __builtin_amdgcn_mfma_f32_16x16x32_bf16(a1f, b1, acc[nt], 0, 0, 0);
  }

  // alphas from fp32 h fragments
  {
    const float* u1 = uvec;
    const float* u2 = uvec + HID;
    f32x4 ua = *(const f32x4*)(u1 + g * 8),      ub = *(const f32x4*)(u1 + g * 8 + 4);
    f32x4 uc = *(const f32x4*)(u1 + 32 + g * 8), ud = *(const f32x4*)(u1 + 32 + g * 8 + 4);
    float p1 = f0[0]*ua[0]+f0[1]*ua[1]+f0[2]*ua[2]+f0[3]*ua[3]
             + f1[0]*ub[0]+f1[1]*ub[1]+f1[2]*ub[2]+f1[3]*ub[3]
             + f2v[0]*uc[0]+f2v[1]*uc[1]+f2v[2]*uc[2]+f2v[3]*uc[3]
             + f3[0]*ud[0]+f3[1]*ud[1]+f3[2]*ud[2]+f3[3]*ud[3];
    ua = *(const f32x4*)(u2 + g * 8);      ub = *(const f32x4*)(u2 + g * 8 + 4);
    uc = *(const f32x4*)(u2 + 32 + g * 8); ud = *(const f32x4*)(u2 + 32 + g * 8 + 4);
    float p2 = f0[0]*ua[0]+f0[1]*ua[1]+f0[2]*ua[2]+f0[3]*ua[3]
             + f1[0]*ub[0]+f1[1]*ub[1]+f1[2]*ub[2]+f1[3]*ub[3]
             + f2v[0]*uc[0]+f2v[1]*uc[1]+f2v[2]*uc[2]+f2v[3]*uc[3]
             + f3[0]*ud[0]+f3[1]*ud[1]+f3[2]*ud[2]+f3[3]*ud[3];
    p1 += __shfl_xor(p1, 16, 64); p1 += __shfl_xor(p1, 32, 64);
    p2 += __shfl_xor(p2, 16, 64); p2 += __shfl_xor(p2, 32, 64);
    if (g == 0 && rowok) {
      alpha1[row] = p1 + ucst[0];
      alpha2[row] = p2 + ucst[1];
    }
  }

  // store hl (+bias). D layout: col = nt*16 + r, node = nb + g*4 + reg
#pragma unroll
  for (int nt = 0; nt < 4; ++nt) {
    float bv = bias[nt * 16 + r];
#pragma unroll
    for (int reg = 0; reg < 4; ++reg) {
      int n2 = nb + g * 4 + reg;
      if (n2 < N_NODES)
        hl[(size_t)n2 * HID + nt * 16 + r] = acc[nt][reg] + bv;
    }
  }
}

// ---------------- edge scores + block max partials ----------------
__global__ void k_score(const int* __restrict__ ei,
                        const float* __restrict__ alpha1,
                        const float* __restrict__ alpha2,
                        const float* __restrict__ attB,
                        float* __restrict__ s,
                        float* __restrict__ partial) {
  __shared__ float red[256];
  int e = blockIdx.x * 256 + threadIdx.x;
  float v = -INFINITY;
  if (e < N_EDGES) {
    int r = ei[e], c = ei[N_EDGES + e];
    float sc = alpha1[r] + alpha2[c] + attB[0];
    sc = sc > 0.f ? sc : SLOPE * sc;
    s[e] = sc;
    v = sc;
  }
  red[threadIdx.x] = v;
  __syncthreads();
  for (int st = 128; st > 0; st >>= 1) {
    if (threadIdx.x < st) red[threadIdx.x] = fmaxf(red[threadIdx.x], red[threadIdx.x + st]);
    __syncthreads();
  }
  if (threadIdx.x == 0) partial[blockIdx.x] = red[0];
}

__global__ void k_reduce_max(const float* __restrict__ partial, int n, float* __restrict__ red) {
  __shared__ float sm[1024];
  float v = -INFINITY;
  for (int i = threadIdx.x; i < n; i += 1024) v = fmaxf(v, partial[i]);
  sm[threadIdx.x] = v;
  __syncthreads();
  for (int st = 512; st > 0; st >>= 1) {
    if (threadIdx.x < st) sm[threadIdx.x] = fmaxf(sm[threadIdx.x], sm[threadIdx.x + st]);
    __syncthreads();
  }
  if (threadIdx.x == 0) red[0] = sm[0];
}

// ---------------- p = exp(s-max); coef[pos[e]] = p*ew; block-sum p ----------------
__global__ void k_exp(const float* __restrict__ s,
                      const float* __restrict__ red,   // red[0] = max
                      const float* __restrict__ ew,
                      const int* __restrict__ pos,
                      float* __restrict__ coef,
                      float* __restrict__ partial) {
  __shared__ float sm[256];
  int e = blockIdx.x * 256 + threadIdx.x;
  float v = 0.f;
  if (e < N_EDGES) {
    float p = expf(s[e] - red[0]);
    coef[pos[e]] = p * ew[e];
    v = p;
  }
  sm[threadIdx.x] = v;
  __syncthreads();
  for (int st = 128; st > 0; st >>= 1) {
    if (threadIdx.x < st) sm[threadIdx.x] += sm[threadIdx.x + st];
    __syncthreads();
  }
  if (threadIdx.x == 0) partial[blockIdx.x] = sm[0];
}

__global__ void k_reduce_sum(const float* __restrict__ partial, int n, float* __restrict__ red) {
  __shared__ float sm[1024];
  float v = 0.f;
  for (int i = threadIdx.x; i < n; i += 1024) v += partial[i];
  sm[threadIdx.x] = v;
  __syncthreads();
  for (int st = 512; st > 0; st >>= 1) {
    if (threadIdx.x < st) sm[threadIdx.x] += sm[threadIdx.x + st];
    __syncthreads();
  }
  if (threadIdx.x == 0) red[0] = sm[0];
}

// ---------------- fused CSR aggregate + relu + LN + residual ----------------
__global__ void k_agg_update(const int* __restrict__ rowptr,
                             const int* __restrict__ deg,
                             const int* __restrict__ col_sorted,
                             const float* __restrict__ coef,
                             const float* __restrict__ red,  // red[1] = sumexp
                             const float* __restrict__ hl,
                             const float* __restrict__ g,
                             const float* __restrict__ b,
                             float* __restrict__ h) {
  int wave = threadIdx.x >> 6, lane = threadIdx.x & 63;
  int n = blockIdx.x * 4 + wave;
  if (n >= N_NODES) return;
  int beg = rowptr[n];
  int end = beg + deg[n];
  float acc = 0.f;
  int k = beg;
  for (; k + 1 < end; k += 2) {
    int c0 = col_sorted[k], c1 = col_sorted[k + 1];
    float w0 = coef[k], w1 = coef[k + 1];
    float v0 = hl[(size_t)c0 * HID + lane];
    float v1 = hl[(size_t)c1 * HID + lane];
    acc += w0 * v0;
    acc += w1 * v1;
  }
  if (k < end) acc += coef[k] * hl[(size_t)col_sorted[k] * HID + lane];

  float inv = 1.0f / red[1];
  float v = hl[(size_t)n * HID + lane] + acc * inv;
  v = fmaxf(v, 0.f);
  float m = v;
#pragma unroll
  for (int off = 32; off > 0; off >>= 1) m += __shfl_xor(m, off, 64);
  m *= (1.0f / HID);
  float d = v - m;
  float var = d * d;
#pragma unroll
  for (int off = 32; off > 0; off >>= 1) var += __shfl_xor(var, off, 64);
  var *= (1.0f / HID);
  float nv = d * rsqrtf(var + LN_EPS);
  h[(size_t)n * HID + lane] += nv * g[lane] + b[lane];
}

// ---------------- output head ----------------
__global__ void k_out(const float* __restrict__ h,
                      const float* __restrict__ W1,  // [64][32]
                      const float* __restrict__ b1,  // [32]
                      const float* __restrict__ W2,  // [32]
                      const float* __restrict__ b2,  // [1]
                      float* __restrict__ out) {
  __shared__ float sW1[HID * 32];
  __shared__ float sW2[32];
  for (int i = threadIdx.x; i < HID * 32; i += blockDim.x) sW1[i] = W1[i];
  if (threadIdx.x < 32) sW2[threadIdx.x] = W2[threadIdx.x];
  __syncthreads();
  int wave = threadIdx.x >> 6, lane = threadIdx.x & 63;
  int n = blockIdx.x * 4 + wave;
  if (n >= N_NODES) return;
  float hreg = h[n * HID + lane];
  int m = lane & 31;
  float z = b1[m];
#pragma unroll
  for (int k = 0; k < HID; ++k)
    z += __shfl(hreg, k, 64) * sW1[k * 32 + m];
  float part = fmaxf(z, 0.f) * sW2[m] * 0.5f;
#pragma unroll
  for (int off = 32; off > 0; off >>= 1) part += __shfl_xor(part, off, 64);
  if (lane == 0) {
    float t = part + b2[0];
    out[n] = 1.0f / (1.0f + expf(-t));
  }
}

extern "C" void kernel_launch(void* const* d_in, const int* in_sizes, int n_in,
                              void* d_out, int out_size, void* d_ws, size_t ws_size,
                              hipStream_t stream) {
  const float* x      = (const float*)d_in[0];
  const int*   ei     = (const int*)d_in[1];     // [2][E]
  const float* ew     = (const float*)d_in[2];
  const float* in_W   = (const float*)d_in[3];
  const float* in_b   = (const float*)d_in[4];
  const float* lin_W  = (const float*)d_in[5];   // [3][64][64]
  const float* lin_b  = (const float*)d_in[6];   // [3][64]
  const float* att_W  = (const float*)d_in[7];   // [3][128]
  const float* att_b  = (const float*)d_in[8];   // [3]
  const float* ln_g   = (const float*)d_in[9];   // [3][64]
  const float* ln_b   = (const float*)d_in[10];  // [3][64]
  const float* out1_W = (const float*)d_in[11];  // [64][32]
  const float* out1_b = (const float*)d_in[12];  // [32]
  const float* out2_W = (const float*)d_in[13];  // [32]
  const float* out2_b = (const float*)d_in[14];  // [1]
  float* out = (float*)d_out;

  float* ws = (float*)d_ws;
  float* h      = ws;                          // 6.4M f
  float* hl     = h + (size_t)N_NODES * HID;   // 6.4M f
  float* coef   = hl + (size_t)N_NODES * HID;  // 1.25M f
  float* alpha1 = coef + N_EDGES;
  float* alpha2 = alpha1 + N_NODES;
  float* s      = alpha2 + N_NODES;            // 1.25M f
  float* part   = s + N_EDGES;                 // 8192
  float* red    = part + 8192;                 // [0]=max, [1]=sum
  float* uvec   = red + 2;                     // [3][2][64]
  float* ucst   = uvec + 3 * 2 * HID;          // [3][2]
  int* deg        = (int*)(ucst + 8);
  int* rowptr     = deg + N_NODES;
  int* cursor     = rowptr + N_NODES;
  int* col_sorted = cursor + N_NODES;          // 1.25M i
  int* pos        = col_sorted + N_EDGES;      // 1.25M i
  int* bsum       = pos + N_EDGES;             // 128

  // ---- one-time CSR build ----
  hipMemsetAsync(deg, 0, N_NODES * sizeof(int), stream);
  k_hist<<<EDGE_TBLOCKS, 256, 0, stream>>>(ei, deg);
  k_blocksums<<<SCAN_BLOCKS, 1024, 0, stream>>>(deg, bsum);
  k_scan_bsums<<<1, 128, 0, stream>>>(bsum, SCAN_BLOCKS);
  k_scan_final<<<SCAN_BLOCKS, 1024, 0, stream>>>(deg, bsum, rowptr, cursor);
  k_fill<<<EDGE_TBLOCKS, 256, 0, stream>>>(ei, cursor, col_sorted, pos);

  k_prep<<<N_LAYERS, 64, 0, stream>>>(lin_W, lin_b, att_W, uvec, ucst);
  k_in_proj<<<NODE_BLOCKS, 256, 0, stream>>>(x, in_W, in_b, h);

  for (int i = 0; i < N_LAYERS; ++i) {
    k_lin_mfma<<<MFMA_BLOCKS, 256, 0, stream>>>(h, lin_W + i * HID * HID, lin_b + i * HID,
                                                uvec + i * 128, ucst + i * 2,
                                                hl, alpha1, alpha2);
    k_score<<<EDGE_TBLOCKS, 256, 0, stream>>>(ei, alpha1, alpha2, att_b + i, s, part);
    k_reduce_max<<<1, 1024, 0, stream>>>(part, EDGE_TBLOCKS, red);
    k_exp<<<EDGE_TBLOCKS, 256, 0, stream>>>(s, red, ew, pos, coef, part);
    k_reduce_sum<<<1, 1024, 0, stream>>>(part, EDGE_TBLOCKS, red + 1);
    k_agg_update<<<NODE_BLOCKS, 256, 0, stream>>>(rowptr, deg, col_sorted, coef, red,
                                                  hl, ln_g + i * HID, ln_b + i * HID, h);
  }

  k_out<<<NODE_BLOCKS, 256, 0, stream>>>(h, out1_W, out1_b, out2_W, out2_b, out);
}

// Round 4
// 578.080 us; speedup vs baseline: 2.6094x; 1.2286x over previous
//
#include <hip/hip_runtime.h>
#include <math.h>

#define N_NODES 100000
#define N_EDGES 1250000
#define IN_DIM 12
#define HID 64
#define N_LAYERS 3
#define LN_EPS 1e-5f
#define SLOPE 0.01f

#define NODE_BLOCKS ((N_NODES + 3) / 4)     // 4 waves (nodes) per 256-thread block
#define EDGE_TBLOCKS ((N_EDGES + 255) / 256)
#define SCAN_BLOCKS ((N_NODES + 1023) / 1024)   // 98
#define MFMA_BLOCKS ((N_NODES + 63) / 64)       // 64 nodes per 256-thread block

typedef short bf16x8 __attribute__((ext_vector_type(8)));
typedef float f32x4 __attribute__((ext_vector_type(4)));

static __device__ __forceinline__ unsigned short f2bf(float f) {
  union { float f; unsigned int u; } v; v.f = f;
  unsigned int r = v.u + 0x7FFFu + ((v.u >> 16) & 1u);   // RNE
  return (unsigned short)(r >> 16);
}
static __device__ __forceinline__ float bf2f(unsigned short u) {
  union { unsigned int u; float f; } v; v.u = ((unsigned int)u) << 16;
  return v.f;
}

// ---------------- input projection: h = x @ in_W + in_b ----------------
__global__ void k_in_proj(const float* __restrict__ x,
                          const float* __restrict__ W,   // [12][64]
                          const float* __restrict__ b,
                          float* __restrict__ h) {
  __shared__ float sW[IN_DIM * HID];
  for (int i = threadIdx.x; i < IN_DIM * HID; i += blockDim.x) sW[i] = W[i];
  __syncthreads();
  int wave = threadIdx.x >> 6, lane = threadIdx.x & 63;
  int n = blockIdx.x * 4 + wave;
  if (n >= N_NODES) return;
  float acc = b[lane];
#pragma unroll
  for (int k = 0; k < IN_DIM; ++k)
    acc += x[n * IN_DIM + k] * sW[k * HID + lane];
  h[n * HID + lane] = acc;
}

// ---------------- CSR build (once per launch) ----------------
__global__ void k_hist(const int* __restrict__ ei, int* __restrict__ deg) {
  int e = blockIdx.x * 256 + threadIdx.x;
  if (e >= N_EDGES) return;
  atomicAdd(&deg[ei[e]], 1);
}

__global__ void k_blocksums(const int* __restrict__ deg, int* __restrict__ bsum) {
  __shared__ int sm[1024];
  int i = blockIdx.x * 1024 + threadIdx.x;
  sm[threadIdx.x] = (i < N_NODES) ? deg[i] : 0;
  __syncthreads();
  for (int st = 512; st > 0; st >>= 1) {
    if (threadIdx.x < st) sm[threadIdx.x] += sm[threadIdx.x + st];
    __syncthreads();
  }
  if (threadIdx.x == 0) bsum[blockIdx.x] = sm[0];
}

__global__ void k_scan_bsums(int* __restrict__ bsum, int nb) {  // single block, 128 thr
  __shared__ int sm[128];
  int v = (threadIdx.x < nb) ? bsum[threadIdx.x] : 0;
  sm[threadIdx.x] = v;
  __syncthreads();
  for (int st = 1; st < 128; st <<= 1) {
    int t = (threadIdx.x >= st) ? sm[threadIdx.x - st] : 0;
    __syncthreads();
    sm[threadIdx.x] += t;
    __syncthreads();
  }
  if (threadIdx.x < nb) bsum[threadIdx.x] = sm[threadIdx.x] - v;  // exclusive
}

__global__ void k_scan_final(const int* __restrict__ deg, const int* __restrict__ bsum,
                             int* __restrict__ rowptr, int* __restrict__ cursor) {
  __shared__ int sm[1024];
  int i = blockIdx.x * 1024 + threadIdx.x;
  int v = (i < N_NODES) ? deg[i] : 0;
  sm[threadIdx.x] = v;
  __syncthreads();
  for (int st = 1; st < 1024; st <<= 1) {
    int t = (threadIdx.x >= st) ? sm[threadIdx.x - st] : 0;
    __syncthreads();
    sm[threadIdx.x] += t;
    __syncthreads();
  }
  int excl = sm[threadIdx.x] - v + bsum[blockIdx.x];
  if (i < N_NODES) { rowptr[i] = excl; cursor[i] = excl; }
}

__global__ void k_fill(const int* __restrict__ ei, int* __restrict__ cursor,
                       int* __restrict__ col_sorted, int* __restrict__ pos) {
  int e = blockIdx.x * 256 + threadIdx.x;
  if (e >= N_EDGES) return;
  int r = ei[e], c = ei[N_EDGES + e];
  int p = atomicAdd(&cursor[r], 1);
  col_sorted[p] = c;
  pos[e] = p;
}

// ---------------- per-layer u = W @ a  (alpha decomposition) ----------------
__global__ void k_prep(const float* __restrict__ lin_W,  // [3][64][64]
                       const float* __restrict__ lin_b,  // [3][64]
                       const float* __restrict__ att_W,  // [3][128]
                       float* __restrict__ uvec,         // [3][2][64]
                       float* __restrict__ ucst) {       // [3][2]
  int l = blockIdx.x, j = threadIdx.x;
  const float* Wl = lin_W + l * HID * HID;
  const float* a1 = att_W + l * 2 * HID;
  const float* a2 = a1 + HID;
  float s1 = 0.f, s2 = 0.f;
  for (int c = 0; c < HID; ++c) {
    float w = Wl[j * HID + c];
    s1 += w * a1[c];
    s2 += w * a2[c];
  }
  uvec[l * 128 + j] = s1;
  uvec[l * 128 + 64 + j] = s2;
  float t1 = lin_b[l * HID + j] * a1[j];
  float t2 = lin_b[l * HID + j] * a2[j];
#pragma unroll
  for (int off = 32; off > 0; off >>= 1) {
    t1 += __shfl_xor(t1, off, 64);
    t2 += __shfl_xor(t2, off, 64);
  }
  if (j == 0) { ucst[l * 2] = t1; ucst[l * 2 + 1] = t2; }
}

// ---------------- MFMA linear: hl = h@W + b (fp32 + bf16 mirror); alphas ----------------
__global__ void k_lin_mfma(const float* __restrict__ h,
                           const float* __restrict__ W,     // [64][64] this layer
                           const float* __restrict__ bias,  // [64]
                           const float* __restrict__ uvec,  // [2][64] this layer
                           const float* __restrict__ ucst,  // [2]
                           float* __restrict__ hl,
                           unsigned short* __restrict__ hl2, // bf16 mirror
                           float* __restrict__ alpha1,
                           float* __restrict__ alpha2) {
  __shared__ unsigned short Wt[HID * 72];  // Wt[n][k] bf16, row stride 72
  for (int idx = threadIdx.x; idx < HID * HID; idx += 256) {
    int k = idx >> 6, n = idx & 63;
    Wt[n * 72 + k] = f2bf(W[idx]);
  }
  __syncthreads();

  int wave = threadIdx.x >> 6, lane = threadIdx.x & 63;
  int g = lane >> 4, r = lane & 15;
  int nb = blockIdx.x * 64 + wave * 16;
  int row = nb + r;
  bool rowok = row < N_NODES;

  f32x4 f0 = {0,0,0,0}, f1 = {0,0,0,0}, f2v = {0,0,0,0}, f3 = {0,0,0,0};
  if (rowok) {
    const float* hrow = h + (size_t)row * HID;
    f0  = *(const f32x4*)(hrow + g * 8);
    f1  = *(const f32x4*)(hrow + g * 8 + 4);
    f2v = *(const f32x4*)(hrow + 32 + g * 8);
    f3  = *(const f32x4*)(hrow + 32 + g * 8 + 4);
  }
  bf16x8 a0, a1f;
#pragma unroll
  for (int i = 0; i < 4; ++i) {
    a0[i]      = (short)f2bf(f0[i]);
    a0[i + 4]  = (short)f2bf(f1[i]);
    a1f[i]     = (short)f2bf(f2v[i]);
    a1f[i + 4] = (short)f2bf(f3[i]);
  }

  f32x4 acc[4] = {{0,0,0,0},{0,0,0,0},{0,0,0,0},{0,0,0,0}};
#pragma unroll
  for (int nt = 0; nt < 4; ++nt) {
    bf16x8 b0 = *(const bf16x8*)&Wt[(nt * 16 + r) * 72 + g * 8];
    bf16x8 b1 = *(const bf16x8*)&Wt[(nt * 16 + r) * 72 + 32 + g * 8];
    acc[nt] = __builtin_amdgcn_mfma_f32_16x16x32_bf16(a0, b0, acc[nt], 0, 0, 0);
    acc[nt] = __builtin_amdgcn_mfma_f32_16x16x32_bf16(a1f, b1, acc[nt], 0, 0, 0);
  }

  // alphas from fp32 h fragments
  {
    const float* u1 = uvec;
    const float* u2 = uvec + HID;
    f32x4 ua = *(const f32x4*)(u1 + g * 8),      ub = *(const f32x4*)(u1 + g * 8 + 4);
    f32x4 uc = *(const f32x4*)(u1 + 32 + g * 8), ud = *(const f32x4*)(u1 + 32 + g * 8 + 4);
    float p1 = f0[0]*ua[0]+f0[1]*ua[1]+f0[2]*ua[2]+f0[3]*ua[3]
             + f1[0]*ub[0]+f1[1]*ub[1]+f1[2]*ub[2]+f1[3]*ub[3]
             + f2v[0]*uc[0]+f2v[1]*uc[1]+f2v[2]*uc[2]+f2v[3]*uc[3]
             + f3[0]*ud[0]+f3[1]*ud[1]+f3[2]*ud[2]+f3[3]*ud[3];
    ua = *(const f32x4*)(u2 + g * 8);      ub = *(const f32x4*)(u2 + g * 8 + 4);
    uc = *(const f32x4*)(u2 + 32 + g * 8); ud = *(const f32x4*)(u2 + 32 + g * 8 + 4);
    float p2 = f0[0]*ua[0]+f0[1]*ua[1]+f0[2]*ua[2]+f0[3]*ua[3]
             + f1[0]*ub[0]+f1[1]*ub[1]+f1[2]*ub[2]+f1[3]*ub[3]
             + f2v[0]*uc[0]+f2v[1]*uc[1]+f2v[2]*uc[2]+f2v[3]*uc[3]
             + f3[0]*ud[0]+f3[1]*ud[1]+f3[2]*ud[2]+f3[3]*ud[3];
    p1 += __shfl_xor(p1, 16, 64); p1 += __shfl_xor(p1, 32, 64);
    p2 += __shfl_xor(p2, 16, 64); p2 += __shfl_xor(p2, 32, 64);
    if (g == 0 && rowok) {
      alpha1[row] = p1 + ucst[0];
      alpha2[row] = p2 + ucst[1];
    }
  }

  // store hl (+bias) fp32 + bf16 mirror. D: col = nt*16 + r, node = nb + g*4 + reg
#pragma unroll
  for (int nt = 0; nt < 4; ++nt) {
    float bv = bias[nt * 16 + r];
#pragma unroll
    for (int reg = 0; reg < 4; ++reg) {
      int n2 = nb + g * 4 + reg;
      if (n2 < N_NODES) {
        float v = acc[nt][reg] + bv;
        hl[(size_t)n2 * HID + nt * 16 + r] = v;
        hl2[(size_t)n2 * HID + nt * 16 + r] = f2bf(v);
      }
    }
  }
}

// ---------------- edge scores + block max partials ----------------
__global__ void k_score(const int* __restrict__ ei,
                        const float* __restrict__ alpha1,
                        const float* __restrict__ alpha2,
                        const float* __restrict__ attB,
                        float* __restrict__ s,
                        float* __restrict__ partial) {
  __shared__ float red[256];
  int e = blockIdx.x * 256 + threadIdx.x;
  float v = -INFINITY;
  if (e < N_EDGES) {
    int r = ei[e], c = ei[N_EDGES + e];
    float sc = alpha1[r] + alpha2[c] + attB[0];
    sc = sc > 0.f ? sc : SLOPE * sc;
    s[e] = sc;
    v = sc;
  }
  red[threadIdx.x] = v;
  __syncthreads();
  for (int st = 128; st > 0; st >>= 1) {
    if (threadIdx.x < st) red[threadIdx.x] = fmaxf(red[threadIdx.x], red[threadIdx.x + st]);
    __syncthreads();
  }
  if (threadIdx.x == 0) partial[blockIdx.x] = red[0];
}

__global__ void k_reduce_max(const float* __restrict__ partial, int n, float* __restrict__ red) {
  __shared__ float sm[1024];
  float v = -INFINITY;
  for (int i = threadIdx.x; i < n; i += 1024) v = fmaxf(v, partial[i]);
  sm[threadIdx.x] = v;
  __syncthreads();
  for (int st = 512; st > 0; st >>= 1) {
    if (threadIdx.x < st) sm[threadIdx.x] = fmaxf(sm[threadIdx.x], sm[threadIdx.x + st]);
    __syncthreads();
  }
  if (threadIdx.x == 0) red[0] = sm[0];
}

// ---------------- p = exp(s-max); coef[pos[e]] = p*ew; block-sum p ----------------
__global__ void k_exp(const float* __restrict__ s,
                      const float* __restrict__ red,   // red[0] = max
                      const float* __restrict__ ew,
                      const int* __restrict__ pos,
                      float* __restrict__ coef,
                      float* __restrict__ partial) {
  __shared__ float sm[256];
  int e = blockIdx.x * 256 + threadIdx.x;
  float v = 0.f;
  if (e < N_EDGES) {
    float p = expf(s[e] - red[0]);
    coef[pos[e]] = p * ew[e];
    v = p;
  }
  sm[threadIdx.x] = v;
  __syncthreads();
  for (int st = 128; st > 0; st >>= 1) {
    if (threadIdx.x < st) sm[threadIdx.x] += sm[threadIdx.x + st];
    __syncthreads();
  }
  if (threadIdx.x == 0) partial[blockIdx.x] = sm[0];
}

__global__ void k_reduce_sum(const float* __restrict__ partial, int n, float* __restrict__ red) {
  __shared__ float sm[1024];
  float v = 0.f;
  for (int i = threadIdx.x; i < n; i += 1024) v += partial[i];
  sm[threadIdx.x] = v;
  __syncthreads();
  for (int st = 512; st > 0; st >>= 1) {
    if (threadIdx.x < st) sm[threadIdx.x] += sm[threadIdx.x + st];
    __syncthreads();
  }
  if (threadIdx.x == 0) red[0] = sm[0];
}

// ---------------- fused CSR aggregate (bf16 gather) + relu + LN + residual ----------------
__global__ void k_agg_update(const int* __restrict__ rowptr,
                             const int* __restrict__ deg,
                             const int* __restrict__ col_sorted,
                             const float* __restrict__ coef,
                             const float* __restrict__ red,  // red[1] = sumexp
                             const float* __restrict__ hl,
                             const unsigned short* __restrict__ hl2,
                             const float* __restrict__ g,
                             const float* __restrict__ b,
                             float* __restrict__ h) {
  int wave = threadIdx.x >> 6, lane = threadIdx.x & 63;
  int n = blockIdx.x * 4 + wave;
  if (n >= N_NODES) return;
  int beg = rowptr[n];
  int end = beg + deg[n];
  float acc = 0.f;
  int k = beg;
  for (; k + 3 < end; k += 4) {
    int c0 = col_sorted[k],     c1 = col_sorted[k + 1];
    int c2 = col_sorted[k + 2], c3 = col_sorted[k + 3];
    float w0 = coef[k], w1 = coef[k + 1], w2 = coef[k + 2], w3 = coef[k + 3];
    float v0 = bf2f(hl2[(size_t)c0 * HID + lane]);
    float v1 = bf2f(hl2[(size_t)c1 * HID + lane]);
    float v2 = bf2f(hl2[(size_t)c2 * HID + lane]);
    float v3 = bf2f(hl2[(size_t)c3 * HID + lane]);
    acc += w0 * v0 + w1 * v1 + w2 * v2 + w3 * v3;
  }
  for (; k < end; ++k)
    acc += coef[k] * bf2f(hl2[(size_t)col_sorted[k] * HID + lane]);

  float inv = 1.0f / red[1];
  float v = hl[(size_t)n * HID + lane] + acc * inv;
  v = fmaxf(v, 0.f);
  float m = v;
#pragma unroll
  for (int off = 32; off > 0; off >>= 1) m += __shfl_xor(m, off, 64);
  m *= (1.0f / HID);
  float d = v - m;
  float var = d * d;
#pragma unroll
  for (int off = 32; off > 0; off >>= 1) var += __shfl_xor(var, off, 64);
  var *= (1.0f / HID);
  float nv = d * rsqrtf(var + LN_EPS);
  h[(size_t)n * HID + lane] += nv * g[lane] + b[lane];
}

// ---------------- output head via MFMA ----------------
// z = relu(h@W1+b1) [N,32]; out = sigmoid(z@W2+b2)
__global__ void k_out_mfma(const float* __restrict__ h,
                           const float* __restrict__ W1,  // [64][32]
                           const float* __restrict__ b1,  // [32]
                           const float* __restrict__ W2,  // [32]
                           const float* __restrict__ b2,  // [1]
                           float* __restrict__ out) {
  __shared__ unsigned short W1t[32 * 72];  // W1t[m][k] bf16
  __shared__ float sW2[32];
  for (int idx = threadIdx.x; idx < HID * 32; idx += 256) {
    int k = idx >> 5, m = idx & 31;
    W1t[m * 72 + k] = f2bf(W1[idx]);
  }
  if (threadIdx.x < 32) sW2[threadIdx.x] = W2[threadIdx.x];
  __syncthreads();

  int wave = threadIdx.x >> 6, lane = threadIdx.x & 63;
  int g = lane >> 4, r = lane & 15;
  int nb = blockIdx.x * 64 + wave * 16;
  int row = nb + r;
  bool rowok = row < N_NODES;

  f32x4 f0 = {0,0,0,0}, f1 = {0,0,0,0}, f2v = {0,0,0,0}, f3 = {0,0,0,0};
  if (rowok) {
    const float* hrow = h + (size_t)row * HID;
    f0  = *(const f32x4*)(hrow + g * 8);
    f1  = *(const f32x4*)(hrow + g * 8 + 4);
    f2v = *(const f32x4*)(hrow + 32 + g * 8);
    f3  = *(const f32x4*)(hrow + 32 + g * 8 + 4);
  }
  bf16x8 a0, a1f;
#pragma unroll
  for (int i = 0; i < 4; ++i) {
    a0[i]      = (short)f2bf(f0[i]);
    a0[i + 4]  = (short)f2bf(f1[i]);
    a1f[i]     = (short)f2bf(f2v[i]);
    a1f[i + 4] = (short)f2bf(f3[i]);
  }

  f32x4 acc[2] = {{0,0,0,0},{0,0,0,0}};
#pragma unroll
  for (int mt = 0; mt < 2; ++mt) {
    bf16x8 b0 = *(const bf16x8*)&W1t[(mt * 16 + r) * 72 + g * 8];
    bf16x8 b1v = *(const bf16x8*)&W1t[(mt * 16 + r) * 72 + 32 + g * 8];
    acc[mt] = __builtin_amdgcn_mfma_f32_16x16x32_bf16(a0, b0, acc[mt], 0, 0, 0);
    acc[mt] = __builtin_amdgcn_mfma_f32_16x16x32_bf16(a1f, b1v, acc[mt], 0, 0, 0);
  }

  // lane holds z[node = nb+g*4+reg][col = mt*16+r] in acc[mt][reg]
  float part[4];
#pragma unroll
  for (int reg = 0; reg < 4; ++reg) {
    float p = 0.f;
#pragma unroll
    for (int mt = 0; mt < 2; ++mt) {
      float z = acc[mt][reg] + b1[mt * 16 + r];
      p += fmaxf(z, 0.f) * sW2[mt * 16 + r];
    }
    // reduce over r (16 lanes in group g)
    p += __shfl_xor(p, 1, 64);
    p += __shfl_xor(p, 2, 64);
    p += __shfl_xor(p, 4, 64);
    p += __shfl_xor(p, 8, 64);
    part[reg] = p;
  }
  if (r == 0) {
    float bb = b2[0];
#pragma unroll
    for (int reg = 0; reg < 4; ++reg) {
      int n2 = nb + g * 4 + reg;
      if (n2 < N_NODES)
        out[n2] = 1.0f / (1.0f + expf(-(part[reg] + bb)));
    }
  }
}

extern "C" void kernel_launch(void* const* d_in, const int* in_sizes, int n_in,
                              void* d_out, int out_size, void* d_ws, size_t ws_size,
                              hipStream_t stream) {
  const float* x      = (const float*)d_in[0];
  const int*   ei     = (const int*)d_in[1];     // [2][E]
  const float* ew     = (const float*)d_in[2];
  const float* in_W   = (const float*)d_in[3];
  const float* in_b   = (const float*)d_in[4];
  const float* lin_W  = (const float*)d_in[5];   // [3][64][64]
  const float* lin_b  = (const float*)d_in[6];   // [3][64]
  const float* att_W  = (const float*)d_in[7];   // [3][128]
  const float* att_b  = (const float*)d_in[8];   // [3]
  const float* ln_g   = (const float*)d_in[9];   // [3][64]
  const float* ln_b   = (const float*)d_in[10];  // [3][64]
  const float* out1_W = (const float*)d_in[11];  // [64][32]
  const float* out1_b = (const float*)d_in[12];  // [32]
  const float* out2_W = (const float*)d_in[13];  // [32]
  const float* out2_b = (const float*)d_in[14];  // [1]
  float* out = (float*)d_out;

  float* ws = (float*)d_ws;
  float* h      = ws;                          // 6.4M f
  float* hl     = h + (size_t)N_NODES * HID;   // 6.4M f
  float* coef   = hl + (size_t)N_NODES * HID;  // 1.25M f
  float* alpha1 = coef + N_EDGES;
  float* alpha2 = alpha1 + N_NODES;
  float* s      = alpha2 + N_NODES;            // 1.25M f
  float* part   = s + N_EDGES;                 // 8192
  float* red    = part + 8192;                 // [0]=max, [1]=sum
  float* uvec   = red + 2;                     // [3][2][64]
  float* ucst   = uvec + 3 * 2 * HID;          // [3][2]
  int* deg        = (int*)(ucst + 8);
  int* rowptr     = deg + N_NODES;
  int* cursor     = rowptr + N_NODES;
  int* col_sorted = cursor + N_NODES;          // 1.25M i
  int* pos        = col_sorted + N_EDGES;      // 1.25M i
  int* bsum       = pos + N_EDGES;             // 128
  unsigned short* hl2 = (unsigned short*)(bsum + 128);  // 6.4M bf16

  // ---- one-time CSR build ----
  hipMemsetAsync(deg, 0, N_NODES * sizeof(int), stream);
  k_hist<<<EDGE_TBLOCKS, 256, 0, stream>>>(ei, deg);
  k_blocksums<<<SCAN_BLOCKS, 1024, 0, stream>>>(deg, bsum);
  k_scan_bsums<<<1, 128, 0, stream>>>(bsum, SCAN_BLOCKS);
  k_scan_final<<<SCAN_BLOCKS, 1024, 0, stream>>>(deg, bsum, rowptr, cursor);
  k_fill<<<EDGE_TBLOCKS, 256, 0, stream>>>(ei, cursor, col_sorted, pos);

  k_prep<<<N_LAYERS, 64, 0, stream>>>(lin_W, lin_b, att_W, uvec, ucst);
  k_in_proj<<<NODE_BLOCKS, 256, 0, stream>>>(x, in_W, in_b, h);

  for (int i = 0; i < N_LAYERS; ++i) {
    k_lin_mfma<<<MFMA_BLOCKS, 256, 0, stream>>>(h, lin_W + i * HID * HID, lin_b + i * HID,
                                                uvec + i * 128, ucst + i * 2,
                                                hl, hl2, alpha1, alpha2);
    k_score<<<EDGE_TBLOCKS, 256, 0, stream>>>(ei, alpha1, alpha2, att_b + i, s, part);
    k_reduce_max<<<1, 1024, 0, stream>>>(part, EDGE_TBLOCKS, red);
    k_exp<<<EDGE_TBLOCKS, 256, 0, stream>>>(s, red, ew, pos, coef, part);
    k_reduce_sum<<<1, 1024, 0, stream>>>(part, EDGE_TBLOCKS, red + 1);
    k_agg_update<<<NODE_BLOCKS, 256, 0, stream>>>(rowptr, deg, col_sorted, coef, red,
                                                  hl, hl2, ln_g + i * HID, ln_b + i * HID, h);
  }

  k_out_mfma<<<MFMA_BLOCKS, 256, 0, stream>>>(h, out1_W, out1_b, out2_W, out2_b, out);
}

// Round 5
// 509.590 us; speedup vs baseline: 2.9601x; 1.1344x over previous
//
#include <hip/hip_runtime.h>
#include <math.h>

#define N_NODES 100000
#define N_EDGES 1250000
#define IN_DIM 12
#define HID 64
#define N_LAYERS 3
#define LN_EPS 1e-5f
#define SLOPE 0.01f

#define NODE_BLOCKS ((N_NODES + 3) / 4)     // 4 waves (nodes) per 256-thread block
#define EDGE_TBLOCKS ((N_EDGES + 255) / 256)
#define SCAN_BLOCKS ((N_NODES + 1023) / 1024)   // 98
#define MFMA_BLOCKS ((N_NODES + 63) / 64)       // 64 nodes per 256-thread block
#define EDGE_CHUNK 2048
#define EDGE_BLOCKS ((N_EDGES + EDGE_CHUNK - 1) / EDGE_CHUNK)   // 611

typedef short bf16x8 __attribute__((ext_vector_type(8)));
typedef float f32x4 __attribute__((ext_vector_type(4)));

static __device__ __forceinline__ unsigned short f2bf(float f) {
  union { float f; unsigned int u; } v; v.f = f;
  unsigned int r = v.u + 0x7FFFu + ((v.u >> 16) & 1u);   // RNE
  return (unsigned short)(r >> 16);
}
static __device__ __forceinline__ float bf2f(unsigned short u) {
  union { unsigned int u; float f; } v; v.u = ((unsigned int)u) << 16;
  return v.f;
}

// ---------------- input projection: h = x @ in_W + in_b ----------------
__global__ void k_in_proj(const float* __restrict__ x,
                          const float* __restrict__ W,   // [12][64]
                          const float* __restrict__ b,
                          float* __restrict__ h) {
  __shared__ float sW[IN_DIM * HID];
  for (int i = threadIdx.x; i < IN_DIM * HID; i += blockDim.x) sW[i] = W[i];
  __syncthreads();
  int wave = threadIdx.x >> 6, lane = threadIdx.x & 63;
  int n = blockIdx.x * 4 + wave;
  if (n >= N_NODES) return;
  float acc = b[lane];
#pragma unroll
  for (int k = 0; k < IN_DIM; ++k)
    acc += x[n * IN_DIM + k] * sW[k * HID + lane];
  h[n * HID + lane] = acc;
}

// ---------------- CSR build (once per launch) ----------------
__global__ void k_hist(const int* __restrict__ ei, int* __restrict__ deg) {
  int e = blockIdx.x * 256 + threadIdx.x;
  if (e >= N_EDGES) return;
  atomicAdd(&deg[ei[e]], 1);
}

__global__ void k_blocksums(const int* __restrict__ deg, int* __restrict__ bsum) {
  __shared__ int sm[1024];
  int i = blockIdx.x * 1024 + threadIdx.x;
  sm[threadIdx.x] = (i < N_NODES) ? deg[i] : 0;
  __syncthreads();
  for (int st = 512; st > 0; st >>= 1) {
    if (threadIdx.x < st) sm[threadIdx.x] += sm[threadIdx.x + st];
    __syncthreads();
  }
  if (threadIdx.x == 0) bsum[blockIdx.x] = sm[0];
}

__global__ void k_scan_bsums(int* __restrict__ bsum, int nb) {  // single block, 128 thr
  __shared__ int sm[128];
  int v = (threadIdx.x < nb) ? bsum[threadIdx.x] : 0;
  sm[threadIdx.x] = v;
  __syncthreads();
  for (int st = 1; st < 128; st <<= 1) {
    int t = (threadIdx.x >= st) ? sm[threadIdx.x - st] : 0;
    __syncthreads();
    sm[threadIdx.x] += t;
    __syncthreads();
  }
  if (threadIdx.x < nb) bsum[threadIdx.x] = sm[threadIdx.x] - v;  // exclusive
}

__global__ void k_scan_final(const int* __restrict__ deg, const int* __restrict__ bsum,
                             int* __restrict__ rowptr, int* __restrict__ cursor) {
  __shared__ int sm[1024];
  int i = blockIdx.x * 1024 + threadIdx.x;
  int v = (i < N_NODES) ? deg[i] : 0;
  sm[threadIdx.x] = v;
  __syncthreads();
  for (int st = 1; st < 1024; st <<= 1) {
    int t = (threadIdx.x >= st) ? sm[threadIdx.x - st] : 0;
    __syncthreads();
    sm[threadIdx.x] += t;
    __syncthreads();
  }
  int excl = sm[threadIdx.x] - v + bsum[blockIdx.x];
  if (i < N_NODES) { rowptr[i] = excl; cursor[i] = excl; }
}

// scatter one 8B record per edge: (col, log(ew))
__global__ void k_fill(const int* __restrict__ ei, const float* __restrict__ ew,
                       int* __restrict__ cursor, uint2* __restrict__ col_lew) {
  int e = blockIdx.x * 256 + threadIdx.x;
  if (e >= N_EDGES) return;
  int r = ei[e], c = ei[N_EDGES + e];
  int p = atomicAdd(&cursor[r], 1);
  uint2 rec;
  rec.x = (unsigned)c;
  rec.y = __float_as_uint(__logf(ew[e]));
  col_lew[p] = rec;
}

// rows_sorted: sequential fill from rowptr/deg (no scatter)
__global__ void k_rows(const int* __restrict__ rowptr, const int* __restrict__ deg,
                       int* __restrict__ rows_sorted) {
  int n = blockIdx.x * 256 + threadIdx.x;
  if (n >= N_NODES) return;
  int beg = rowptr[n], d = deg[n];
  for (int i = 0; i < d; ++i) rows_sorted[beg + i] = n;
}

// ---------------- per-layer u = W @ a  (alpha decomposition) ----------------
__global__ void k_prep(const float* __restrict__ lin_W,  // [3][64][64]
                       const float* __restrict__ lin_b,  // [3][64]
                       const float* __restrict__ att_W,  // [3][128]
                       float* __restrict__ uvec,         // [3][2][64]
                       float* __restrict__ ucst) {       // [3][2]
  int l = blockIdx.x, j = threadIdx.x;
  const float* Wl = lin_W + l * HID * HID;
  const float* a1 = att_W + l * 2 * HID;
  const float* a2 = a1 + HID;
  float s1 = 0.f, s2 = 0.f;
  for (int c = 0; c < HID; ++c) {
    float w = Wl[j * HID + c];
    s1 += w * a1[c];
    s2 += w * a2[c];
  }
  uvec[l * 128 + j] = s1;
  uvec[l * 128 + 64 + j] = s2;
  float t1 = lin_b[l * HID + j] * a1[j];
  float t2 = lin_b[l * HID + j] * a2[j];
#pragma unroll
  for (int off = 32; off > 0; off >>= 1) {
    t1 += __shfl_xor(t1, off, 64);
    t2 += __shfl_xor(t2, off, 64);
  }
  if (j == 0) { ucst[l * 2] = t1; ucst[l * 2 + 1] = t2; }
}

// ---------------- MFMA linear: hl = h@W + b (fp32 + bf16 mirror); alphas ----------------
__global__ void k_lin_mfma(const float* __restrict__ h,
                           const float* __restrict__ W,     // [64][64] this layer
                           const float* __restrict__ bias,  // [64]
                           const float* __restrict__ uvec,  // [2][64] this layer
                           const float* __restrict__ ucst,  // [2]
                           float* __restrict__ hl,
                           unsigned short* __restrict__ hl2, // bf16 mirror
                           float* __restrict__ alpha1,
                           float* __restrict__ alpha2) {
  __shared__ unsigned short Wt[HID * 72];  // Wt[n][k] bf16, row stride 72
  for (int idx = threadIdx.x; idx < HID * HID; idx += 256) {
    int k = idx >> 6, n = idx & 63;
    Wt[n * 72 + k] = f2bf(W[idx]);
  }
  __syncthreads();

  int wave = threadIdx.x >> 6, lane = threadIdx.x & 63;
  int g = lane >> 4, r = lane & 15;
  int nb = blockIdx.x * 64 + wave * 16;
  int row = nb + r;
  bool rowok = row < N_NODES;

  f32x4 f0 = {0,0,0,0}, f1 = {0,0,0,0}, f2v = {0,0,0,0}, f3 = {0,0,0,0};
  if (rowok) {
    const float* hrow = h + (size_t)row * HID;
    f0  = *(const f32x4*)(hrow + g * 8);
    f1  = *(const f32x4*)(hrow + g * 8 + 4);
    f2v = *(const f32x4*)(hrow + 32 + g * 8);
    f3  = *(const f32x4*)(hrow + 32 + g * 8 + 4);
  }
  bf16x8 a0, a1f;
#pragma unroll
  for (int i = 0; i < 4; ++i) {
    a0[i]      = (short)f2bf(f0[i]);
    a0[i + 4]  = (short)f2bf(f1[i]);
    a1f[i]     = (short)f2bf(f2v[i]);
    a1f[i + 4] = (short)f2bf(f3[i]);
  }

  f32x4 acc[4] = {{0,0,0,0},{0,0,0,0},{0,0,0,0},{0,0,0,0}};
#pragma unroll
  for (int nt = 0; nt < 4; ++nt) {
    bf16x8 b0 = *(const bf16x8*)&Wt[(nt * 16 + r) * 72 + g * 8];
    bf16x8 b1 = *(const bf16x8*)&Wt[(nt * 16 + r) * 72 + 32 + g * 8];
    acc[nt] = __builtin_amdgcn_mfma_f32_16x16x32_bf16(a0, b0, acc[nt], 0, 0, 0);
    acc[nt] = __builtin_amdgcn_mfma_f32_16x16x32_bf16(a1f, b1, acc[nt], 0, 0, 0);
  }

  // alphas from fp32 h fragments
  {
    const float* u1 = uvec;
    const float* u2 = uvec + HID;
    f32x4 ua = *(const f32x4*)(u1 + g * 8),      ub = *(const f32x4*)(u1 + g * 8 + 4);
    f32x4 uc = *(const f32x4*)(u1 + 32 + g * 8), ud = *(const f32x4*)(u1 + 32 + g * 8 + 4);
    float p1 = f0[0]*ua[0]+f0[1]*ua[1]+f0[2]*ua[2]+f0[3]*ua[3]
             + f1[0]*ub[0]+f1[1]*ub[1]+f1[2]*ub[2]+f1[3]*ub[3]
             + f2v[0]*uc[0]+f2v[1]*uc[1]+f2v[2]*uc[2]+f2v[3]*uc[3]
             + f3[0]*ud[0]+f3[1]*ud[1]+f3[2]*ud[2]+f3[3]*ud[3];
    ua = *(const f32x4*)(u2 + g * 8);      ub = *(const f32x4*)(u2 + g * 8 + 4);
    uc = *(const f32x4*)(u2 + 32 + g * 8); ud = *(const f32x4*)(u2 + 32 + g * 8 + 4);
    float p2 = f0[0]*ua[0]+f0[1]*ua[1]+f0[2]*ua[2]+f0[3]*ua[3]
             + f1[0]*ub[0]+f1[1]*ub[1]+f1[2]*ub[2]+f1[3]*ub[3]
             + f2v[0]*uc[0]+f2v[1]*uc[1]+f2v[2]*uc[2]+f2v[3]*uc[3]
             + f3[0]*ud[0]+f3[1]*ud[1]+f3[2]*ud[2]+f3[3]*ud[3];
    p1 += __shfl_xor(p1, 16, 64); p1 += __shfl_xor(p1, 32, 64);
    p2 += __shfl_xor(p2, 16, 64); p2 += __shfl_xor(p2, 32, 64);
    if (g == 0 && rowok) {
      alpha1[row] = p1 + ucst[0];
      alpha2[row] = p2 + ucst[1];
    }
  }

  // store hl (+bias) fp32 + bf16 mirror. D: col = nt*16 + r, node = nb + g*4 + reg
#pragma unroll
  for (int nt = 0; nt < 4; ++nt) {
    float bv = bias[nt * 16 + r];
#pragma unroll
    for (int reg = 0; reg < 4; ++reg) {
      int n2 = nb + g * 4 + reg;
      if (n2 < N_NODES) {
        float v = acc[nt][reg] + bv;
        hl[(size_t)n2 * HID + nt * 16 + r] = v;
        hl2[(size_t)n2 * HID + nt * 16 + r] = f2bf(v);
      }
    }
  }
}

// ---------------- per-layer edge pass: score + online max/sum, sequential ----------------
__global__ void k_edge(const int* __restrict__ rows_sorted,
                       const uint2* __restrict__ col_lew,
                       const float* __restrict__ alpha1,
                       const float* __restrict__ alpha2,
                       const float* __restrict__ attB,
                       float* __restrict__ s,
                       float* __restrict__ pmax,
                       float* __restrict__ psum) {
  int t = threadIdx.x;
  int base = blockIdx.x * EDGE_CHUNK;
  float ab = attB[0];
  float m = -INFINITY, sum = 0.f;
#pragma unroll
  for (int i = 0; i < 8; ++i) {
    int p = base + i * 256 + t;
    if (p < N_EDGES) {
      uint2 rec = col_lew[p];
      int r = rows_sorted[p];
      float sc = alpha1[r] + alpha2[rec.x] + ab;
      sc = sc > 0.f ? sc : SLOPE * sc;
      s[p] = sc;
      if (sc > m) { sum *= __expf(m - sc); m = sc; }
      sum += __expf(sc - m);
    }
  }
  __shared__ float smax[256], ssum[256];
  smax[t] = m; ssum[t] = sum;
  __syncthreads();
  for (int st = 128; st > 0; st >>= 1) {
    if (t < st) {
      float ma = smax[t], mb = smax[t + st];
      float sa = ssum[t], sb = ssum[t + st];
      float mm = fmaxf(ma, mb);
      float ss = 0.f;
      if (mm != -INFINITY)
        ss = (ma == -INFINITY ? 0.f : sa * __expf(ma - mm))
           + (mb == -INFINITY ? 0.f : sb * __expf(mb - mm));
      smax[t] = mm; ssum[t] = ss;
    }
    __syncthreads();
  }
  if (t == 0) { pmax[blockIdx.x] = smax[0]; psum[blockIdx.x] = ssum[0]; }
}

// combine block partials -> red[0]=M, red[1]=S (single block)
__global__ void k_combine(const float* __restrict__ pmax, const float* __restrict__ psum,
                          int n, float* __restrict__ red) {
  __shared__ float smax[1024], ssum[1024];
  int t = threadIdx.x;
  float m = -INFINITY, s = 0.f;
  for (int i = t; i < n; i += 1024) {
    float mb = pmax[i], sb = psum[i];
    if (mb != -INFINITY) {
      if (mb > m) { s *= __expf(m - mb); m = mb; }
      s += sb * __expf(mb - m);
    }
  }
  smax[t] = m; ssum[t] = s;
  __syncthreads();
  for (int st = 512; st > 0; st >>= 1) {
    if (t < st) {
      float ma = smax[t], mb = smax[t + st];
      float sa = ssum[t], sb = ssum[t + st];
      float mm = fmaxf(ma, mb);
      float ss = 0.f;
      if (mm != -INFINITY)
        ss = (ma == -INFINITY ? 0.f : sa * __expf(ma - mm))
           + (mb == -INFINITY ? 0.f : sb * __expf(mb - mm));
      smax[t] = mm; ssum[t] = ss;
    }
    __syncthreads();
  }
  if (t == 0) { red[0] = smax[0]; red[1] = ssum[0]; }
}

// ---------------- fused CSR aggregate (bf16 gather) + relu + LN + residual ----------------
__global__ void k_agg_update(const int* __restrict__ rowptr,
                             const int* __restrict__ deg,
                             const uint2* __restrict__ col_lew,
                             const float* __restrict__ s,
                             const float* __restrict__ red,  // [0]=M, [1]=S
                             const float* __restrict__ hl,
                             const unsigned short* __restrict__ hl2,
                             const float* __restrict__ g,
                             const float* __restrict__ b,
                             float* __restrict__ h) {
  int wave = threadIdx.x >> 6, lane = threadIdx.x & 63;
  int n = blockIdx.x * 4 + wave;
  if (n >= N_NODES) return;
  float M = red[0];
  int beg = rowptr[n];
  int end = beg + deg[n];
  float acc = 0.f;
  int k = beg;
  for (; k + 3 < end; k += 4) {
    uint2 r0 = col_lew[k],     r1 = col_lew[k + 1];
    uint2 r2 = col_lew[k + 2], r3 = col_lew[k + 3];
    float w0 = __expf(s[k]     + __uint_as_float(r0.y) - M);
    float w1 = __expf(s[k + 1] + __uint_as_float(r1.y) - M);
    float w2 = __expf(s[k + 2] + __uint_as_float(r2.y) - M);
    float w3 = __expf(s[k + 3] + __uint_as_float(r3.y) - M);
    float v0 = bf2f(hl2[(size_t)r0.x * HID + lane]);
    float v1 = bf2f(hl2[(size_t)r1.x * HID + lane]);
    float v2 = bf2f(hl2[(size_t)r2.x * HID + lane]);
    float v3 = bf2f(hl2[(size_t)r3.x * HID + lane]);
    acc += w0 * v0 + w1 * v1 + w2 * v2 + w3 * v3;
  }
  for (; k < end; ++k) {
    uint2 r0 = col_lew[k];
    acc += __expf(s[k] + __uint_as_float(r0.y) - M) * bf2f(hl2[(size_t)r0.x * HID + lane]);
  }

  float inv = 1.0f / red[1];
  float v = hl[(size_t)n * HID + lane] + acc * inv;
  v = fmaxf(v, 0.f);
  float m = v;
#pragma unroll
  for (int off = 32; off > 0; off >>= 1) m += __shfl_xor(m, off, 64);
  m *= (1.0f / HID);
  float d = v - m;
  float var = d * d;
#pragma unroll
  for (int off = 32; off > 0; off >>= 1) var += __shfl_xor(var, off, 64);
  var *= (1.0f / HID);
  float nv = d * rsqrtf(var + LN_EPS);
  h[(size_t)n * HID + lane] += nv * g[lane] + b[lane];
}

// ---------------- output head via MFMA ----------------
__global__ void k_out_mfma(const float* __restrict__ h,
                           const float* __restrict__ W1,  // [64][32]
                           const float* __restrict__ b1,  // [32]
                           const float* __restrict__ W2,  // [32]
                           const float* __restrict__ b2,  // [1]
                           float* __restrict__ out) {
  __shared__ unsigned short W1t[32 * 72];  // W1t[m][k] bf16
  __shared__ float sW2[32];
  for (int idx = threadIdx.x; idx < HID * 32; idx += 256) {
    int k = idx >> 5, m = idx & 31;
    W1t[m * 72 + k] = f2bf(W1[idx]);
  }
  if (threadIdx.x < 32) sW2[threadIdx.x] = W2[threadIdx.x];
  __syncthreads();

  int wave = threadIdx.x >> 6, lane = threadIdx.x & 63;
  int g = lane >> 4, r = lane & 15;
  int nb = blockIdx.x * 64 + wave * 16;
  int row = nb + r;
  bool rowok = row < N_NODES;

  f32x4 f0 = {0,0,0,0}, f1 = {0,0,0,0}, f2v = {0,0,0,0}, f3 = {0,0,0,0};
  if (rowok) {
    const float* hrow = h + (size_t)row * HID;
    f0  = *(const f32x4*)(hrow + g * 8);
    f1  = *(const f32x4*)(hrow + g * 8 + 4);
    f2v = *(const f32x4*)(hrow + 32 + g * 8);
    f3  = *(const f32x4*)(hrow + 32 + g * 8 + 4);
  }
  bf16x8 a0, a1f;
#pragma unroll
  for (int i = 0; i < 4; ++i) {
    a0[i]      = (short)f2bf(f0[i]);
    a0[i + 4]  = (short)f2bf(f1[i]);
    a1f[i]     = (short)f2bf(f2v[i]);
    a1f[i + 4] = (short)f2bf(f3[i]);
  }

  f32x4 acc[2] = {{0,0,0,0},{0,0,0,0}};
#pragma unroll
  for (int mt = 0; mt < 2; ++mt) {
    bf16x8 b0 = *(const bf16x8*)&W1t[(mt * 16 + r) * 72 + g * 8];
    bf16x8 b1v = *(const bf16x8*)&W1t[(mt * 16 + r) * 72 + 32 + g * 8];
    acc[mt] = __builtin_amdgcn_mfma_f32_16x16x32_bf16(a0, b0, acc[mt], 0, 0, 0);
    acc[mt] = __builtin_amdgcn_mfma_f32_16x16x32_bf16(a1f, b1v, acc[mt], 0, 0, 0);
  }

  float part[4];
#pragma unroll
  for (int reg = 0; reg < 4; ++reg) {
    float p = 0.f;
#pragma unroll
    for (int mt = 0; mt < 2; ++mt) {
      float z = acc[mt][reg] + b1[mt * 16 + r];
      p += fmaxf(z, 0.f) * sW2[mt * 16 + r];
    }
    p += __shfl_xor(p, 1, 64);
    p += __shfl_xor(p, 2, 64);
    p += __shfl_xor(p, 4, 64);
    p += __shfl_xor(p, 8, 64);
    part[reg] = p;
  }
  if (r == 0) {
    float bb = b2[0];
#pragma unroll
    for (int reg = 0; reg < 4; ++reg) {
      int n2 = nb + g * 4 + reg;
      if (n2 < N_NODES)
        out[n2] = 1.0f / (1.0f + expf(-(part[reg] + bb)));
    }
  }
}

extern "C" void kernel_launch(void* const* d_in, const int* in_sizes, int n_in,
                              void* d_out, int out_size, void* d_ws, size_t ws_size,
                              hipStream_t stream) {
  const float* x      = (const float*)d_in[0];
  const int*   ei     = (const int*)d_in[1];     // [2][E]
  const float* ew     = (const float*)d_in[2];
  const float* in_W   = (const float*)d_in[3];
  const float* in_b   = (const float*)d_in[4];
  const float* lin_W  = (const float*)d_in[5];   // [3][64][64]
  const float* lin_b  = (const float*)d_in[6];   // [3][64]
  const float* att_W  = (const float*)d_in[7];   // [3][128]
  const float* att_b  = (const float*)d_in[8];   // [3]
  const float* ln_g   = (const float*)d_in[9];   // [3][64]
  const float* ln_b   = (const float*)d_in[10];  // [3][64]
  const float* out1_W = (const float*)d_in[11];  // [64][32]
  const float* out1_b = (const float*)d_in[12];  // [32]
  const float* out2_W = (const float*)d_in[13];  // [32]
  const float* out2_b = (const float*)d_in[14];  // [1]
  float* out = (float*)d_out;

  float* ws = (float*)d_ws;
  float* h           = ws;                        // [0, 6.4M)
  float* hl          = ws + 6400000;              // 6.4M
  unsigned short* hl2 = (unsigned short*)(ws + 12800000);   // 3.2M floats worth
  uint2* col_lew     = (uint2*)(ws + 16000000);   // 1.25M x 8B (8B-aligned offset)
  float* s           = ws + 18500000;             // 1.25M
  int* rows_sorted   = (int*)(ws + 19750000);     // 1.25M
  int* deg           = (int*)(ws + 21000000);
  int* rowptr        = (int*)(ws + 21100000);
  int* cursor        = (int*)(ws + 21200000);
  float* alpha1      = ws + 21300000;
  float* alpha2      = ws + 21400000;
  float* pmax        = ws + 21500000;             // 1024
  float* psum        = ws + 21501024;             // 1024
  float* red         = ws + 21502048;             // [0]=M, [1]=S
  float* uvec        = ws + 21502050;             // [3][2][64]
  float* ucst        = ws + 21502434;             // [3][2]
  int* bsum          = (int*)(ws + 21502442);     // 128

  // ---- one-time CSR build ----
  hipMemsetAsync(deg, 0, N_NODES * sizeof(int), stream);
  k_hist<<<EDGE_TBLOCKS, 256, 0, stream>>>(ei, deg);
  k_blocksums<<<SCAN_BLOCKS, 1024, 0, stream>>>(deg, bsum);
  k_scan_bsums<<<1, 128, 0, stream>>>(bsum, SCAN_BLOCKS);
  k_scan_final<<<SCAN_BLOCKS, 1024, 0, stream>>>(deg, bsum, rowptr, cursor);
  k_fill<<<EDGE_TBLOCKS, 256, 0, stream>>>(ei, ew, cursor, col_lew);
  k_rows<<<(N_NODES + 255) / 256, 256, 0, stream>>>(rowptr, deg, rows_sorted);

  k_prep<<<N_LAYERS, 64, 0, stream>>>(lin_W, lin_b, att_W, uvec, ucst);
  k_in_proj<<<NODE_BLOCKS, 256, 0, stream>>>(x, in_W, in_b, h);

  for (int i = 0; i < N_LAYERS; ++i) {
    k_lin_mfma<<<MFMA_BLOCKS, 256, 0, stream>>>(h, lin_W + i * HID * HID, lin_b + i * HID,
                                                uvec + i * 128, ucst + i * 2,
                                                hl, hl2, alpha1, alpha2);
    k_edge<<<EDGE_BLOCKS, 256, 0, stream>>>(rows_sorted, col_lew, alpha1, alpha2,
                                            att_b + i, s, pmax, psum);
    k_combine<<<1, 1024, 0, stream>>>(pmax, psum, EDGE_BLOCKS, red);
    k_agg_update<<<NODE_BLOCKS, 256, 0, stream>>>(rowptr, deg, col_lew, s, red,
                                                  hl, hl2, ln_g + i * HID, ln_b + i * HID, h);
  }

  k_out_mfma<<<MFMA_BLOCKS, 256, 0, stream>>>(h, out1_W, out1_b, out2_W, out2_b, out);
}